// Round 1
// baseline (1878.051 us; speedup 1.0000x reference)
//
#include <hip/hip_runtime.h>
#include <math.h>

#define BB 2
#define CDIM 256
#define NHEADS 8
#define HD 32
#define HH 40
#define WW 40
#define NN 1600
#define C3 768
#define SCALE 0.17677669529663687f  // 1/sqrt(32)

// ---------- helpers ----------
__device__ inline unsigned fkey(float f) {
    unsigned u = __float_as_uint(f);
    return (u & 0x80000000u) ? ~u : (u | 0x80000000u);
}
__device__ inline float finv(unsigned u) {
    unsigned v = (u & 0x80000000u) ? (u ^ 0x80000000u) : ~u;
    return __uint_as_float(v);
}

// ---------- 1x1 conv (qkv projection): out[b,oc,s] = b[oc] + sum_ic w[oc,ic]*x[b,ic,s] ----------
__global__ void conv1x1_kernel(const float* __restrict__ x, const float* __restrict__ w,
                               const float* __restrict__ bias, float* __restrict__ out) {
    int idx = blockIdx.x * 256 + threadIdx.x;   // BB*C3*NN total
    int s = idx % NN;
    int t = idx / NN;
    int oc = t % C3;
    int b = t / C3;
    const float* xb = x + (size_t)b * CDIM * NN + s;
    const float* wr = w + (size_t)oc * CDIM;
    float acc = bias[oc];
#pragma unroll 8
    for (int ic = 0; ic < CDIM; ic++) acc += wr[ic] * xb[(size_t)ic * NN];
    out[idx] = acc;
}

// ---------- depthwise 3x3 pad1 ----------
__global__ void dwconv_kernel(const float* __restrict__ in, const float* __restrict__ w,
                              const float* __restrict__ bias, float* __restrict__ out) {
    int idx = blockIdx.x * 256 + threadIdx.x;
    int s = idx % NN;
    int t = idx / NN;
    int c = t % C3;
    int b = t / C3;
    int y = s / WW, xx = s % WW;
    const float* ib = in + ((size_t)b * C3 + c) * NN;
    const float* wr = w + (size_t)c * 9;
    float acc = bias[c];
#pragma unroll
    for (int ky = 0; ky < 3; ky++) {
        int iy = y + ky - 1;
        if (iy < 0 || iy >= HH) continue;
#pragma unroll
        for (int kx = 0; kx < 3; kx++) {
            int ix = xx + kx - 1;
            if (ix < 0 || ix >= WW) continue;
            acc += wr[ky * 3 + kx] * ib[iy * WW + ix];
        }
    }
    out[idx] = acc;
}

// ---------- phase 1: per-row entropy of full softmax ----------
__global__ void entropy_kernel(const float* __restrict__ qkv, float* __restrict__ ent_rows) {
    int blk = blockIdx.x;               // (b*NHEADS+h)*NN + row
    int row = blk % NN;
    int bh = blk / NN;
    int h = bh % NHEADS;
    int b = bh / NHEADS;
    __shared__ float att[NN];
    __shared__ float qs[HD];
    __shared__ float red[8];
    int tid = threadIdx.x;
    int lane = tid & 63, wid = tid >> 6;
    const float* qb = qkv + ((size_t)b * C3 + h * HD) * NN;
    const float* kb = qkv + ((size_t)b * C3 + CDIM + h * HD) * NN;
    if (tid < HD) qs[tid] = qb[(size_t)tid * NN + row];
    __syncthreads();
    for (int j = tid; j < NN; j += 256) {
        float acc = 0.f;
#pragma unroll
        for (int d = 0; d < HD; d++) acc += qs[d] * kb[(size_t)d * NN + j];
        att[j] = acc * SCALE;
    }
    __syncthreads();
    float lm = -INFINITY;
    for (int j = tid; j < NN; j += 256) lm = fmaxf(lm, att[j]);
    for (int o = 32; o > 0; o >>= 1) lm = fmaxf(lm, __shfl_down(lm, o));
    if (lane == 0) red[wid] = lm;
    __syncthreads();
    if (tid == 0) red[4] = fmaxf(fmaxf(red[0], red[1]), fmaxf(red[2], red[3]));
    __syncthreads();
    float m = red[4];
    float ls = 0.f, lt = 0.f;
    for (int j = tid; j < NN; j += 256) {
        float z = att[j] - m;
        float e = expf(z);
        ls += e;
        lt += e * z;
    }
    for (int o = 32; o > 0; o >>= 1) {
        ls += __shfl_down(ls, o);
        lt += __shfl_down(lt, o);
    }
    __syncthreads();
    if (lane == 0) { red[wid] = ls; red[4 + wid] = lt; }
    __syncthreads();
    if (tid == 0) {
        float S = red[0] + red[1] + red[2] + red[3];
        float T = red[4] + red[5] + red[6] + red[7];
        // entropy = logS - sum p*(a-m)
        ent_rows[blk] = logf(S) - T / S;
    }
}

// ---------- gate: mean entropy -> tiny MLP -> keep count ----------
__global__ void gate_kernel(const float* __restrict__ ent_rows,
                            const float* __restrict__ g1w, const float* __restrict__ g1b,
                            const float* __restrict__ g2w, const float* __restrict__ g2b,
                            int* __restrict__ keep) {
    int bh = blockIdx.x;
    int tid = threadIdx.x;
    __shared__ float red[4];
    float ls = 0.f;
    for (int j = tid; j < NN; j += 256) ls += ent_rows[bh * NN + j];
    for (int o = 32; o > 0; o >>= 1) ls += __shfl_down(ls, o);
    int lane = tid & 63, wid = tid >> 6;
    if (lane == 0) red[wid] = ls;
    __syncthreads();
    if (tid == 0) {
        float ent = (red[0] + red[1] + red[2] + red[3]) / (float)NN;
        float val = g2b[0];
#pragma unroll
        for (int j = 0; j < 16; j++) {
            float hid = ent * g1w[j] + g1b[j];
            if (hid < 0.f) hid = 0.f;
            val += hid * g2w[j];
        }
        float ratio = 0.9f / (1.f + expf(-val)) + 0.1f;
        int kp = (int)ceilf(ratio * (float)NN);
        if (kp < 1) kp = 1;
        if (kp > NN) kp = NN;
        keep[bh] = kp;
    }
}

// ---------- phase 2: recompute attn row, radix-select kth, sparse softmax, PV ----------
__global__ void sparse_attn_kernel(const float* __restrict__ qkv, const int* __restrict__ keep,
                                   float* __restrict__ out_heads) {
    int blk = blockIdx.x;
    int row = blk % NN;
    int bh = blk / NN;
    int h = bh % NHEADS;
    int b = bh / NHEADS;
    __shared__ float att[NN];
    __shared__ float qs[HD];
    __shared__ float red[8];
    __shared__ unsigned hist[256];
    __shared__ float outl[HD];
    __shared__ int sel[2];
    int tid = threadIdx.x;
    int lane = tid & 63, wid = tid >> 6;
    const float* qb = qkv + ((size_t)b * C3 + h * HD) * NN;
    const float* kb = qkv + ((size_t)b * C3 + CDIM + h * HD) * NN;
    const float* vb = qkv + ((size_t)b * C3 + 2 * CDIM + h * HD) * NN;
    if (tid < HD) qs[tid] = qb[(size_t)tid * NN + row];
    __syncthreads();
    for (int j = tid; j < NN; j += 256) {
        float acc = 0.f;
#pragma unroll
        for (int d = 0; d < HD; d++) acc += qs[d] * kb[(size_t)d * NN + j];
        att[j] = acc * SCALE;
    }
    __syncthreads();
    // row max (always among kept elements)
    float lm = -INFINITY;
    for (int j = tid; j < NN; j += 256) lm = fmaxf(lm, att[j]);
    for (int o = 32; o > 0; o >>= 1) lm = fmaxf(lm, __shfl_down(lm, o));
    if (lane == 0) red[wid] = lm;
    __syncthreads();
    if (tid == 0) red[4] = fmaxf(fmaxf(red[0], red[1]), fmaxf(red[2], red[3]));
    __syncthreads();
    float m = red[4];

    // exact kth-largest via MSB-first radix select on monotone keys
    int want = keep[bh];
    unsigned prefixHigh = 0;
    for (int pass = 0; pass < 4; pass++) {
        int shift = 24 - 8 * pass;
        hist[tid] = 0u;
        __syncthreads();
        for (int j = tid; j < NN; j += 256) {
            unsigned u = fkey(att[j]);
            bool ok = (pass == 0) || ((u >> (shift + 8)) == prefixHigh);
            if (ok) atomicAdd(&hist[(u >> shift) & 255u], 1u);
        }
        __syncthreads();
        if (tid == 0) {
            int cum = 0, bsel = 0, w2 = want;
            for (int bb = 255; bb >= 0; bb--) {
                int c = (int)hist[bb];
                if (cum + c >= want) { bsel = bb; w2 = want - cum; break; }
                cum += c;
            }
            sel[0] = bsel;
            sel[1] = w2;
        }
        __syncthreads();
        prefixHigh = (prefixHigh << 8) | (unsigned)sel[0];
        want = sel[1];
        __syncthreads();
    }
    float kth = finv(prefixHigh);

    // sparse softmax denominator
    float ls = 0.f;
    for (int j = tid; j < NN; j += 256) {
        float a = att[j];
        if (a >= kth) ls += expf(a - m);
    }
    for (int o = 32; o > 0; o >>= 1) ls += __shfl_down(ls, o);
    if (lane == 0) red[wid] = ls;
    __syncthreads();
    if (tid == 0) red[5] = red[0] + red[1] + red[2] + red[3];
    __syncthreads();
    float S = red[5];

    // PV accumulate
    float acc[HD];
#pragma unroll
    for (int d = 0; d < HD; d++) acc[d] = 0.f;
    if (tid < HD) outl[tid] = 0.f;
    __syncthreads();
    for (int j = tid; j < NN; j += 256) {
        float a = att[j];
        if (a >= kth) {
            float p = expf(a - m);
#pragma unroll
            for (int d = 0; d < HD; d++) acc[d] += p * vb[(size_t)d * NN + j];
        }
    }
#pragma unroll
    for (int d = 0; d < HD; d++) {
        float v = acc[d];
        for (int o = 32; o > 0; o >>= 1) v += __shfl_down(v, o);
        if (lane == 0) atomicAdd(&outl[d], v);
    }
    __syncthreads();
    if (tid < HD)
        out_heads[((size_t)b * NN + row) * CDIM + h * HD + tid] = outl[tid] / S;
}

// ---------- output projection: out[b,co,s] = pb[co] + sum_c oh[b,s,c]*pw[co,c] ----------
__global__ void proj_kernel(const float* __restrict__ oh, const float* __restrict__ pw,
                            const float* __restrict__ pb, float* __restrict__ out) {
    int idx = blockIdx.x * 256 + threadIdx.x;  // BB*CDIM*NN
    int s = idx % NN;
    int t = idx / NN;
    int co = t % CDIM;
    int b = t / CDIM;
    const float* ob = oh + ((size_t)b * NN + s) * CDIM;
    const float* wr = pw + (size_t)co * CDIM;
    float acc = pb[co];
#pragma unroll 8
    for (int c = 0; c < CDIM; c++) acc += ob[c] * wr[c];
    out[idx] = acc;
}

extern "C" void kernel_launch(void* const* d_in, const int* in_sizes, int n_in,
                              void* d_out, int out_size, void* d_ws, size_t ws_size,
                              hipStream_t stream) {
    const float* x      = (const float*)d_in[0];
    const float* qkv_w  = (const float*)d_in[1];
    const float* qkv_b  = (const float*)d_in[2];
    const float* pos_w  = (const float*)d_in[3];
    const float* pos_b  = (const float*)d_in[4];
    const float* proj_w = (const float*)d_in[5];
    const float* proj_b = (const float*)d_in[6];
    const float* g1w    = (const float*)d_in[7];
    const float* g1b    = (const float*)d_in[8];
    const float* g2w    = (const float*)d_in[9];
    const float* g2b    = (const float*)d_in[10];
    float* out = (float*)d_out;

    float* ws   = (float*)d_ws;
    float* buf1 = ws;                                  // BB*C3*NN
    float* buf2 = buf1 + (size_t)BB * C3 * NN;         // BB*C3*NN
    float* ent  = buf2 + (size_t)BB * C3 * NN;         // BB*NHEADS*NN
    float* oh   = ent + (size_t)BB * NHEADS * NN;      // BB*NN*CDIM
    int* keep   = (int*)(oh + (size_t)BB * NN * CDIM); // BB*NHEADS ints

    conv1x1_kernel<<<BB * C3 * NN / 256, 256, 0, stream>>>(x, qkv_w, qkv_b, buf1);
    dwconv_kernel<<<BB * C3 * NN / 256, 256, 0, stream>>>(buf1, pos_w, pos_b, buf2);
    entropy_kernel<<<BB * NHEADS * NN, 256, 0, stream>>>(buf2, ent);
    gate_kernel<<<BB * NHEADS, 256, 0, stream>>>(ent, g1w, g1b, g2w, g2b, keep);
    sparse_attn_kernel<<<BB * NHEADS * NN, 256, 0, stream>>>(buf2, keep, oh);
    proj_kernel<<<BB * CDIM * NN / 256, 256, 0, stream>>>(oh, proj_w, proj_b, out);
}

// Round 2
// 593.252 us; speedup vs baseline: 3.1657x; 3.1657x over previous
//
#include <hip/hip_runtime.h>
#include <math.h>

#define BB 2
#define CDIM 256
#define NHEADS 8
#define HD 32
#define HH 40
#define WW 40
#define NN 1600
#define C3 768
#define SCALE 0.17677669529663687f  // 1/sqrt(32)
#define RT 8            // rows per block in attention kernels
#define NRT (NN / RT)   // 200 row-tiles

// ---------- helpers ----------
__device__ inline unsigned fkey(float f) {
    unsigned u = __float_as_uint(f);
    return (u & 0x80000000u) ? ~u : (u | 0x80000000u);
}
__device__ inline float finv(unsigned u) {
    unsigned v = (u & 0x80000000u) ? (u ^ 0x80000000u) : ~u;
    return __uint_as_float(v);
}

// ---------- 1x1 conv: block covers 256 s-positions x 4 output channels ----------
__global__ __launch_bounds__(256) void conv1x1_kernel(const float* __restrict__ x,
                                                      const float* __restrict__ w,
                                                      const float* __restrict__ bias,
                                                      float* __restrict__ out) {
    int blk = blockIdx.x;
    int st = blk % 7;
    int t2 = blk / 7;
    int ocg = t2 % (C3 / 4);
    int b = t2 / (C3 / 4);
    int s = st * 256 + threadIdx.x;
    if (s >= NN) return;
    int oc0 = ocg * 4;
    const float* xb = x + (size_t)b * CDIM * NN + s;
    const float* w0 = w + (size_t)oc0 * CDIM;
    float a0 = bias[oc0], a1 = bias[oc0 + 1], a2 = bias[oc0 + 2], a3 = bias[oc0 + 3];
#pragma unroll 4
    for (int ic = 0; ic < CDIM; ic++) {
        float xv = xb[(size_t)ic * NN];
        a0 += w0[ic] * xv;
        a1 += w0[CDIM + ic] * xv;
        a2 += w0[2 * CDIM + ic] * xv;
        a3 += w0[3 * CDIM + ic] * xv;
    }
    float* ob = out + ((size_t)b * C3 + oc0) * NN + s;
    ob[0] = a0; ob[NN] = a1; ob[2 * NN] = a2; ob[3 * NN] = a3;
}

// ---------- depthwise 3x3 pad1 ----------
__global__ __launch_bounds__(256) void dwconv_kernel(const float* __restrict__ in,
                                                     const float* __restrict__ w,
                                                     const float* __restrict__ bias,
                                                     float* __restrict__ out) {
    int idx = blockIdx.x * 256 + threadIdx.x;
    int s = idx % NN;
    int t = idx / NN;
    int c = t % C3;
    int b = t / C3;
    int y = s / WW, xx = s % WW;
    const float* ib = in + ((size_t)b * C3 + c) * NN;
    const float* wr = w + (size_t)c * 9;
    float acc = bias[c];
#pragma unroll
    for (int ky = 0; ky < 3; ky++) {
        int iy = y + ky - 1;
        if (iy < 0 || iy >= HH) continue;
#pragma unroll
        for (int kx = 0; kx < 3; kx++) {
            int ix = xx + kx - 1;
            if (ix < 0 || ix >= WW) continue;
            acc += wr[ky * 3 + kx] * ib[iy * WW + ix];
        }
    }
    out[idx] = acc;
}

// ---------- phase 1: online-softmax entropy, 8 rows/block, wave owns 2 rows ----------
__global__ __launch_bounds__(256) void entropy_kernel(const float* __restrict__ qkv,
                                                      float* __restrict__ ent) {
    int blk = blockIdx.x;      // bh*NRT + rt
    int rt = blk % NRT;
    int bh = blk / NRT;
    int h = bh % NHEADS, b = bh / NHEADS;
    int row0 = rt * RT;
    __shared__ float Qs[RT][HD];
    int tid = threadIdx.x;
    const float* qb = qkv + ((size_t)b * C3 + h * HD) * NN;
    const float* kb = qkv + ((size_t)b * C3 + CDIM + h * HD) * NN;
    {
        int r = tid >> 5, d = tid & 31;
        Qs[r][d] = qb[(size_t)d * NN + row0 + r];
    }
    __syncthreads();
    int w = tid >> 6, lane = tid & 63;
    int lr0 = 2 * w, lr1 = lr0 + 1;
    float q0[HD], q1[HD];
#pragma unroll
    for (int d = 0; d < HD; d++) { q0[d] = Qs[lr0][d]; q1[d] = Qs[lr1][d]; }
    float m0 = -1e30f, s0 = 0.f, t0 = 0.f;
    float m1 = -1e30f, s1 = 0.f, t1 = 0.f;
    for (int kt = 0; kt < 25; kt++) {
        int j = kt * 64 + lane;
        float kc[HD];
#pragma unroll
        for (int d = 0; d < HD; d++) kc[d] = kb[(size_t)d * NN + j];
        float a0 = 0.f, a1 = 0.f;
#pragma unroll
        for (int d = 0; d < HD; d++) { a0 += q0[d] * kc[d]; a1 += q1[d] * kc[d]; }
        a0 *= SCALE; a1 *= SCALE;
        if (a0 > m0) {
            float c = __expf(m0 - a0);
            t0 = c * (t0 + (m0 - a0) * s0);
            s0 = c * s0 + 1.f;
            m0 = a0;
        } else {
            float z = a0 - m0, e = __expf(z);
            s0 += e; t0 += e * z;
        }
        if (a1 > m1) {
            float c = __expf(m1 - a1);
            t1 = c * (t1 + (m1 - a1) * s1);
            s1 = c * s1 + 1.f;
            m1 = a1;
        } else {
            float z = a1 - m1, e = __expf(z);
            s1 += e; t1 += e * z;
        }
    }
#pragma unroll
    for (int off = 1; off < 64; off <<= 1) {
        float mo = __shfl_xor(m0, off), so = __shfl_xor(s0, off), to = __shfl_xor(t0, off);
        float mn = fmaxf(m0, mo);
        float c1 = __expf(m0 - mn), c2 = __expf(mo - mn);
        t0 = c1 * (t0 + (m0 - mn) * s0) + c2 * (to + (mo - mn) * so);
        s0 = c1 * s0 + c2 * so;
        m0 = mn;
        mo = __shfl_xor(m1, off); so = __shfl_xor(s1, off); to = __shfl_xor(t1, off);
        mn = fmaxf(m1, mo);
        c1 = __expf(m1 - mn); c2 = __expf(mo - mn);
        t1 = c1 * (t1 + (m1 - mn) * s1) + c2 * (to + (mo - mn) * so);
        s1 = c1 * s1 + c2 * so;
        m1 = mn;
    }
    if (lane == 0) ent[(size_t)bh * NN + row0 + lr0] = logf(s0) - t0 / s0;
    if (lane == 1) ent[(size_t)bh * NN + row0 + lr1] = logf(s1) - t1 / s1;
}

// ---------- gate ----------
__global__ void gate_kernel(const float* __restrict__ ent_rows,
                            const float* __restrict__ g1w, const float* __restrict__ g1b,
                            const float* __restrict__ g2w, const float* __restrict__ g2b,
                            int* __restrict__ keep) {
    int bh = blockIdx.x;
    int tid = threadIdx.x;
    __shared__ float red[4];
    float ls = 0.f;
    for (int j = tid; j < NN; j += 256) ls += ent_rows[bh * NN + j];
    for (int o = 32; o > 0; o >>= 1) ls += __shfl_down(ls, o);
    int lane = tid & 63, wid = tid >> 6;
    if (lane == 0) red[wid] = ls;
    __syncthreads();
    if (tid == 0) {
        float ent = (red[0] + red[1] + red[2] + red[3]) / (float)NN;
        float val = g2b[0];
#pragma unroll
        for (int j = 0; j < 16; j++) {
            float hid = ent * g1w[j] + g1b[j];
            if (hid < 0.f) hid = 0.f;
            val += hid * g2w[j];
        }
        float ratio = 0.9f / (1.f + expf(-val)) + 0.1f;
        int kp = (int)ceilf(ratio * (float)NN);
        if (kp < 1) kp = 1;
        if (kp > NN) kp = NN;
        keep[bh] = kp;
    }
}

// ---------- phase 2: 8 rows/block, wave owns 2 rows; parallel radix select ----------
__global__ __launch_bounds__(256) void sparse_attn_kernel(const float* __restrict__ qkv,
                                                          const int* __restrict__ keep,
                                                          float* __restrict__ oht) {
    int blk = blockIdx.x;
    int rt = blk % NRT;
    int bh = blk / NRT;
    int h = bh % NHEADS, b = bh / NHEADS;
    int row0 = rt * RT;
    __shared__ float att[RT][NN];       // 51.2 KB
    __shared__ unsigned hist[RT][256];  // 8 KB
    __shared__ float Qs[RT][HD];        // 1 KB
    int tid = threadIdx.x;
    const float* qb = qkv + ((size_t)b * C3 + h * HD) * NN;
    const float* kb = qkv + ((size_t)b * C3 + CDIM + h * HD) * NN;
    const float* vb = qkv + ((size_t)b * C3 + 2 * CDIM + h * HD) * NN;
    {
        int r = tid >> 5, d = tid & 31;
        Qs[r][d] = qb[(size_t)d * NN + row0 + r];
    }
    __syncthreads();
    int w = tid >> 6, lane = tid & 63;
    int lr0 = 2 * w, lr1 = lr0 + 1;
    float q0[HD], q1[HD];
#pragma unroll
    for (int d = 0; d < HD; d++) { q0[d] = Qs[lr0][d]; q1[d] = Qs[lr1][d]; }

    // ---- QK^T into LDS att rows; track per-row max ----
    float m0 = -1e30f, m1 = -1e30f;
    for (int kt = 0; kt < 25; kt++) {
        int j = kt * 64 + lane;
        float kc[HD];
#pragma unroll
        for (int d = 0; d < HD; d++) kc[d] = kb[(size_t)d * NN + j];
        float a0 = 0.f, a1 = 0.f;
#pragma unroll
        for (int d = 0; d < HD; d++) { a0 += q0[d] * kc[d]; a1 += q1[d] * kc[d]; }
        a0 *= SCALE; a1 *= SCALE;
        att[lr0][j] = a0;
        att[lr1][j] = a1;
        m0 = fmaxf(m0, a0); m1 = fmaxf(m1, a1);
    }
#pragma unroll
    for (int off = 1; off < 64; off <<= 1) {
        m0 = fmaxf(m0, __shfl_xor(m0, off));
        m1 = fmaxf(m1, __shfl_xor(m1, off));
    }

    // ---- radix select kth-largest, per row on a 32-lane half-wave ----
    int l = lane & 31;
    int r = (lane < 32) ? lr0 : lr1;
    int want = keep[bh];
    unsigned prefixHigh = 0;
    for (int pass = 0; pass < 4; pass++) {
        int shift = 24 - 8 * pass;
#pragma unroll
        for (int i = 0; i < 8; i++) hist[r][248 - 8 * l + i] = 0u;
        for (int k2 = 0; k2 < 50; k2++) {
            int j = k2 * 32 + l;
            unsigned u = fkey(att[r][j]);
            bool ok = (pass == 0) || ((u >> (shift + 8)) == prefixHigh);
            if (ok) atomicAdd(&hist[r][(u >> shift) & 255u], 1u);
        }
        unsigned sch = 0;
#pragma unroll
        for (int i = 0; i < 8; i++) sch += hist[r][248 - 8 * l + i];
        unsigned inc = sch;
#pragma unroll
        for (int dlt = 1; dlt < 32; dlt <<= 1) {
            unsigned tv = __shfl_up(inc, dlt, 32);
            if (l >= dlt) inc += tv;
        }
        unsigned pref = inc - sch;
        bool found = (pref < (unsigned)want) && ((unsigned)want <= inc);
        int bsel = -1, wnew = 0;
        if (found) {
            unsigned want2 = (unsigned)want - pref, cum = 0;
#pragma unroll
            for (int i = 0; i < 8; i++) {
                int bbin = 255 - 8 * l - i;
                unsigned c = hist[r][bbin];
                if (bsel < 0 && cum + c >= want2) { bsel = bbin; wnew = (int)(want2 - cum); }
                cum += c;
            }
        }
        unsigned long long mk = __ballot(found);
        int src = (lane < 32) ? __builtin_ctzll(mk & 0xffffffffULL)
                              : __builtin_ctzll(mk >> 32) + 32;
        bsel = __shfl(bsel, src);
        want = __shfl(wnew, src);
        prefixHigh = (prefixHigh << 8) | (unsigned)bsel;
    }
    float kth = finv(prefixHigh);
    float kth0 = __shfl(kth, 0);
    float kth1 = __shfl(kth, 32);

    // ---- fused sparse softmax numerator + PV ----
    float acc0[HD], acc1[HD];
#pragma unroll
    for (int d = 0; d < HD; d++) { acc0[d] = 0.f; acc1[d] = 0.f; }
    float S0 = 0.f, S1 = 0.f;
    for (int kt = 0; kt < 25; kt++) {
        int j = kt * 64 + lane;
        float a0 = att[lr0][j];
        float a1 = att[lr1][j];
        float p0 = (a0 >= kth0) ? __expf(a0 - m0) : 0.f;
        float p1 = (a1 >= kth1) ? __expf(a1 - m1) : 0.f;
        S0 += p0; S1 += p1;
        float vc[HD];
#pragma unroll
        for (int d = 0; d < HD; d++) vc[d] = vb[(size_t)d * NN + j];
#pragma unroll
        for (int d = 0; d < HD; d++) { acc0[d] += p0 * vc[d]; acc1[d] += p1 * vc[d]; }
    }
#pragma unroll
    for (int off = 1; off < 64; off <<= 1) {
        S0 += __shfl_xor(S0, off);
        S1 += __shfl_xor(S1, off);
    }

    // ---- reduce acc over the 64 jj-lanes via per-wave LDS scratch (reuses att rows) ----
    float* scratch = &att[lr0][0];  // 2*1600 floats private to this wave; need 64*33=2112
    int dd = lane & 31;
    int jb = (lane < 32) ? 0 : 32;
#pragma unroll
    for (int d = 0; d < HD; d++) scratch[lane * 33 + d] = acc0[d];
    float sum0 = 0.f;
#pragma unroll
    for (int jj = 0; jj < 32; jj++) sum0 += scratch[(jb + jj) * 33 + dd];
    sum0 += __shfl_xor(sum0, 32);
#pragma unroll
    for (int d = 0; d < HD; d++) scratch[lane * 33 + d] = acc1[d];
    float sum1 = 0.f;
#pragma unroll
    for (int jj = 0; jj < 32; jj++) sum1 += scratch[(jb + jj) * 33 + dd];
    sum1 += __shfl_xor(sum1, 32);

    if (lane < 32) {
        size_t base = ((size_t)b * CDIM + h * HD + dd) * NN + row0;
        oht[base + lr0] = sum0 / S0;
        oht[base + lr1] = sum1 / S1;
    }
}

// ---------- output projection from oht [b][c][n] ----------
__global__ __launch_bounds__(256) void proj_kernel(const float* __restrict__ oht,
                                                   const float* __restrict__ pw,
                                                   const float* __restrict__ pb,
                                                   float* __restrict__ out) {
    int blk = blockIdx.x;
    int st = blk % 7;
    int t2 = blk / 7;
    int ocg = t2 % (CDIM / 4);
    int b = t2 / (CDIM / 4);
    int s = st * 256 + threadIdx.x;
    if (s >= NN) return;
    int co0 = ocg * 4;
    const float* ib = oht + (size_t)b * CDIM * NN + s;
    const float* w0 = pw + (size_t)co0 * CDIM;
    float a0 = pb[co0], a1 = pb[co0 + 1], a2 = pb[co0 + 2], a3 = pb[co0 + 3];
#pragma unroll 4
    for (int c = 0; c < CDIM; c++) {
        float xv = ib[(size_t)c * NN];
        a0 += w0[c] * xv;
        a1 += w0[CDIM + c] * xv;
        a2 += w0[2 * CDIM + c] * xv;
        a3 += w0[3 * CDIM + c] * xv;
    }
    float* ob = out + ((size_t)b * CDIM + co0) * NN + s;
    ob[0] = a0; ob[NN] = a1; ob[2 * NN] = a2; ob[3 * NN] = a3;
}

extern "C" void kernel_launch(void* const* d_in, const int* in_sizes, int n_in,
                              void* d_out, int out_size, void* d_ws, size_t ws_size,
                              hipStream_t stream) {
    const float* x      = (const float*)d_in[0];
    const float* qkv_w  = (const float*)d_in[1];
    const float* qkv_b  = (const float*)d_in[2];
    const float* pos_w  = (const float*)d_in[3];
    const float* pos_b  = (const float*)d_in[4];
    const float* proj_w = (const float*)d_in[5];
    const float* proj_b = (const float*)d_in[6];
    const float* g1w    = (const float*)d_in[7];
    const float* g1b    = (const float*)d_in[8];
    const float* g2w    = (const float*)d_in[9];
    const float* g2b    = (const float*)d_in[10];
    float* out = (float*)d_out;

    float* ws   = (float*)d_ws;
    float* buf1 = ws;                                  // BB*C3*NN
    float* buf2 = buf1 + (size_t)BB * C3 * NN;         // BB*C3*NN
    float* ent  = buf2 + (size_t)BB * C3 * NN;         // BB*NHEADS*NN
    float* oht  = ent + (size_t)BB * NHEADS * NN;      // BB*CDIM*NN  ([b][c][n])
    int* keep   = (int*)(oht + (size_t)BB * CDIM * NN);

    conv1x1_kernel<<<BB * (C3 / 4) * 7, 256, 0, stream>>>(x, qkv_w, qkv_b, buf1);
    dwconv_kernel<<<BB * C3 * NN / 256, 256, 0, stream>>>(buf1, pos_w, pos_b, buf2);
    entropy_kernel<<<NHEADS * BB * NRT, 256, 0, stream>>>(buf2, ent);
    gate_kernel<<<BB * NHEADS, 256, 0, stream>>>(ent, g1w, g1b, g2w, g2b, keep);
    sparse_attn_kernel<<<NHEADS * BB * NRT, 256, 0, stream>>>(buf2, keep, oht);
    proj_kernel<<<BB * (CDIM / 4) * 7, 256, 0, stream>>>(oht, proj_w, proj_b, out);
}